// Round 1
// 119.840 us; speedup vs baseline: 1.0057x; 1.0057x over previous
//
#include <hip/hip_runtime.h>
#include <hip/hip_bf16.h>
#include <math.h>

#define EPS 1e-6f
#define N 64          // INPUT_SIZE == NUM_LEAVES
#define NLAYERS 63
#define SINK_ITERS 20
#define LOG2E 1.4426950408889634f

typedef __attribute__((ext_vector_type(8))) short bf16x8;   // 8 bf16 = 4 VGPRs
typedef __attribute__((ext_vector_type(4))) float f32x4;    // MFMA C/D

__device__ __forceinline__ float fast_log2(float v) {
#if __has_builtin(__builtin_amdgcn_logf)
  return __builtin_amdgcn_logf(v);
#else
  return log2f(v);
#endif
}
__device__ __forceinline__ float fast_exp2(float v) {
#if __has_builtin(__builtin_amdgcn_exp2f)
  return __builtin_amdgcn_exp2f(v);
#else
  return exp2f(v);
#endif
}

// fp32 -> bf16 RNE (bit pattern) — used by the single-wave sinkhorn epilogue.
__device__ __forceinline__ unsigned short f2bf(float f) {
  unsigned int u = __float_as_uint(f);
  return (unsigned short)((u + 0x7FFFu + ((u >> 16) & 1u)) >> 16);
}

// Packed HW convert: 2 f32 -> 2 bf16 in one instruction (RNE on gfx950).
__device__ __forceinline__ unsigned int cvt_pk_bf16(float lo, float hi) {
  unsigned int r;
  asm("v_cvt_pk_bf16_f32 %0, %1, %2" : "=v"(r) : "v"(lo), "v"(hi));
  return r;
}
__device__ __forceinline__ bf16x8 pack8(float4 a, float4 b) {
  union { unsigned int ui[4]; bf16x8 v; } u;
  u.ui[0] = cvt_pk_bf16(a.x, a.y);
  u.ui[1] = cvt_pk_bf16(a.z, a.w);
  u.ui[2] = cvt_pk_bf16(b.x, b.y);
  u.ui[3] = cvt_pk_bf16(b.z, b.w);
  return u.v;
}

// ---------------------------------------------------------------------------
// Kernel 1: Sinkhorn (scaling-vector form, single wave) + P -> MFMA B-fragment
// precompute (bf16) + per-layer scan constants (R15 encoding).
//
// R15 layer encoding [63][8]: {sgn, e1, lcg, cw1 | Sc, Oc, e0, cw0}
//   sgn  = this layer's reflection sign (+1 / -1), off = (1-sgn)/2 derived.
//   Sc_i = sgn_i * sgn_{i-1} (sgn_{-1} := 1)   — composed reflect; clamp
//   Oc_i = (1 - Sc_i)/2                          commutes with reflection.
//   cw0 = cl*w0, cw1 = cl*w1                    — lin branch pre-scaled.
//   lcg = log2(cg) (or -1e30 when cg == 0)      — cg folded into exp2 arg.
//   e0 = 2*w0*p, e1 = 2*w1*p.
// Scan step (state r in pre-unreflect space):
//   cr = clamp(r); xr = Sc*cr + Oc; g = exp2(e0*log2(xr) + e1*log2(yr) + lcg);
//   r' = cw0*xr + cw1*yr + g.   Final: out = sgn_62*r + off_62.
// ---------------------------------------------------------------------------
__global__ __launch_bounds__(64) void sinkhorn_kernel(
    const float* __restrict__ logits,
    const float* __restrict__ weights,
    const float* __restrict__ biases,
    unsigned short* __restrict__ Pfrag,  // [8][64][8] bf16
    float* __restrict__ layers) {        // [63][8]
  __shared__ float T[64 * 65 + 128];
  const int l = threadIdx.x;

  float K[64];
  {
    const float4* lr = (const float4*)(logits + (l << 6));
    #pragma unroll
    for (int q = 0; q < 16; ++q) {
      float4 t = lr[q];
      K[4*q+0] = fast_exp2(t.x * LOG2E);
      K[4*q+1] = fast_exp2(t.y * LOG2E);
      K[4*q+2] = fast_exp2(t.z * LOG2E);
      K[4*q+3] = fast_exp2(t.w * LOG2E);
    }
  }
  #pragma unroll
  for (int j = 0; j < 64; ++j) T[l * 65 + j] = K[j];
  __syncthreads();
  float KT[64];
  #pragma unroll
  for (int k = 0; k < 64; ++k) KT[k] = T[k * 65 + l];
  __syncthreads();

  float* Uv = &T[64 * 65];        // 16B-aligned
  float* Vv = &T[64 * 65 + 64];   // 16B-aligned
  const float4* Uv4 = (const float4*)Uv;
  const float4* Vv4 = (const float4*)Vv;
  Vv[l] = 1.0f;
  __syncthreads();

  float u = 1.0f;
  for (int it = 0; it < SINK_ITERS; ++it) {
    float s0 = 0.f, s1 = 0.f, s2 = 0.f, s3 = 0.f;
    #pragma unroll
    for (int q = 0; q < 16; ++q) {
      float4 v = Vv4[q];
      s0 = fmaf(K[4*q+0], v.x, s0);
      s1 = fmaf(K[4*q+1], v.y, s1);
      s2 = fmaf(K[4*q+2], v.z, s2);
      s3 = fmaf(K[4*q+3], v.w, s3);
    }
    u = 1.0f / ((s0 + s1) + (s2 + s3));
    __syncthreads();
    Uv[l] = u;
    __syncthreads();
    float c0 = 0.f, c1 = 0.f, c2 = 0.f, c3 = 0.f;
    #pragma unroll
    for (int q = 0; q < 16; ++q) {
      float4 uu = Uv4[q];
      c0 = fmaf(KT[4*q+0], uu.x, c0);
      c1 = fmaf(KT[4*q+1], uu.y, c1);
      c2 = fmaf(KT[4*q+2], uu.z, c2);
      c3 = fmaf(KT[4*q+3], uu.w, c3);
    }
    float v = 1.0f / ((c0 + c1) + (c2 + c3));
    __syncthreads();
    Vv[l] = v;
    __syncthreads();
  }

  #pragma unroll
  for (int j = 0; j < 64; ++j) T[l * 65 + j] = u * K[j] * Vv[j];
  __syncthreads();

  #pragma unroll
  for (int s = 0; s < 2; ++s)
    #pragma unroll
    for (int t = 0; t < 4; ++t) {
      union { unsigned short us[8]; bf16x8 v; } buf;
      #pragma unroll
      for (int j = 0; j < 8; ++j)
        buf.us[j] = f2bf(T[(s*32 + ((l >> 4) << 3) + j) * 65 + t*16 + (l & 15)]);
      *(bf16x8*)(Pfrag + (((s*4 + t) * 64 + l) << 3)) = buf.v;
    }

  if (l < NLAYERS) {
    float w0 = weights[l];
    float w1 = 1.0f - w0;
    float a  = biases[l];
    float sgn, e0, e1, cw0, cw1, lcg;
    if (fabsf(a - 0.5f) < EPS) {
      sgn = 1.f; e0 = 0.f; e1 = 0.f; cw0 = w0; cw1 = w1; lcg = -1.0e30f;
    } else {
      float ae;
      if (a < 0.5f) { sgn = -1.f; ae = fminf(fmaxf(1.0f - a, -1.0f + EPS), 2.0f - EPS); }
      else          { sgn =  1.f; ae = a; }
      float pp = sqrtf(3.0f / fmaxf(2.0f - ae, EPS)) - 1.0f;
      float cl, cg;
      if (ae >= 0.75f) { cl = 0.0f;            cg = 1.0f; }
      else             { cl = 3.0f - 4.0f*ae;  cg = 4.0f*ae - 2.0f; }
      e0  = 2.0f * w0 * pp;
      e1  = 2.0f * w1 * pp;
      cw0 = cl * w0;
      cw1 = cl * w1;
      lcg = (cg > 0.f) ? log2f(cg) : -1.0e30f;
    }
    float sgnp = 1.f;
    if (l > 0) {
      float ap = biases[l - 1];
      sgnp = (fabsf(ap - 0.5f) < EPS) ? 1.f : (ap < 0.5f ? -1.f : 1.f);
    }
    float Sc = sgn * sgnp;
    float Oc = 0.5f - 0.5f * Sc;
    float* Lr = layers + l * 8;
    Lr[0] = sgn; Lr[1] = e1; Lr[2] = lcg; Lr[3] = cw1;
    Lr[4] = Sc;  Lr[5] = Oc; Lr[6] = e0;  Lr[7] = cw0;
  }
}

// ---------------------------------------------------------------------------
// Kernel 2 (R15): R14 + composed-reflection algebra (6-op chain) + 8-step
// chunked precompute (#pragma unroll 1) to cap live VGPRs (~110) so
// __launch_bounds__(256,4) holds 4 blocks/CU (LDS 36.8 KB x 4 = 147 KB).
// Per-chunk leaf reads (2x ds_read_b128) replace the resident 32-reg Lf.
// ---------------------------------------------------------------------------

template<int HALF>
__device__ __forceinline__ void do_gemm(const bf16x8 (&Bf)[2][4],
                                        const bf16x8 (&Af)[4][2],
                                        float* Lv, int w, int q, int c) {
  #pragma unroll
  for (int rt = 0; rt < 4; ++rt) {
    #pragma unroll
    for (int lt = 0; lt < 2; ++lt) {
      f32x4 acc = {0.f, 0.f, 0.f, 0.f};
      acc = __builtin_amdgcn_mfma_f32_16x16x32_bf16(Bf[0][(HALF << 1) + lt], Af[rt][0], acc, 0, 0, 0);
      acc = __builtin_amdgcn_mfma_f32_16x16x32_bf16(Bf[1][(HALF << 1) + lt], Af[rt][1], acc, 0, 0, 0);
      const int row  = (w << 6) + (rt << 4) + c;   // block-local batch row
      const int nloc = (lt << 4) + (q << 2);       // local leaf col 0..28
      *(f32x4*)&Lv[row * 36 + nloc] = acc;         // ds_write_b128 (wave-local)
    }
  }
}

// One 8-step chunk: leaf-side precompute (ILP block) then the dependent chain.
// L0 = global leaf/step base index of this chunk (leaf n pairs with layer n-1).
__device__ __forceinline__ void do_chunk(int L0, const float* Lrow,
                                         const float4* Lp4, float& r) {
  const int loc = L0 & 31;
  f32x4 lf0 = *(const f32x4*)&Lrow[loc];
  f32x4 lf1 = *(const f32x4*)&Lrow[loc + 4];
  float lf[8] = {lf0[0], lf0[1], lf0[2], lf0[3], lf1[0], lf1[1], lf1[2], lf1[3]};

  float ylin[8], ylg[8];
  #pragma unroll
  for (int k = 0; k < 8; ++k) {
    if (L0 + k >= 1) {                              // only k==0 can be step 0
      float4 p0 = Lp4[(L0 + k - 1) * 2];            // {sgn, e1, lcg, cw1}
      float off = fmaf(-0.5f, p0.x, 0.5f);
      float yy  = fminf(fmaxf(lf[k], EPS), 1.0f - EPS);
      float yr  = fmaf(p0.x, yy, off);
      float ly  = fast_log2(yr);
      ylg[k]  = fmaf(p0.y, ly, p0.z);               // e1*log2(yr) + log2(cg)
      ylin[k] = p0.w * yr;                          // cl*w1*yr
    }
  }

  // Dependent chain, 6 ops on the critical path:
  //   med3 -> fma(reflect) -> log -> fma -> exp -> add  (lin fma is parallel)
  #pragma unroll
  for (int k = 0; k < 8; ++k) {
    if (L0 + k >= 1) {
      float4 p1 = Lp4[(L0 + k - 1) * 2 + 1];        // {Sc, Oc, e0, cw0}
      float cr = fminf(fmaxf(r, EPS), 1.0f - EPS);  // v_med3_f32
      float xr = fmaf(p1.x, cr, p1.y);              // composed reflect
      float lx = fast_log2(xr);
      float g  = fast_exp2(fmaf(p1.z, lx, ylg[k])); // cg * x'^e0 * y'^e1
      r = fmaf(p1.w, xr, ylin[k]) + g;              // cl*lin + cg*g
    } else {
      r = lf[0];                                    // state_0 = leaf_0
    }
  }
}

__global__ __launch_bounds__(256, 4) void scan_kernel(
    const float* __restrict__ x,
    const unsigned short* __restrict__ Pfrag,
    const float* __restrict__ layers,
    float* __restrict__ out) {
  __shared__ float Lv[256 * 36];
  const int tid = threadIdx.x;
  const int w = tid >> 6, l = tid & 63;
  const int q = l >> 4, c = l & 15;
  const size_t rowbase = (size_t)blockIdx.x << 8;   // 256 rows per block
  const float4* Lp4 = (const float4*)layers;        // uniform -> s_load_dwordx4

  // ---- A fragments (x rows): issue HBM loads first, then pack via cvt_pk.
  float4 xa[4][4];
  #pragma unroll
  for (int i = 0; i < 4; ++i) {
    const float* rp = x + (rowbase + (w << 6) + (i << 4) + c) * 64 + (q << 3);
    xa[i][0] = *(const float4*)(rp);
    xa[i][1] = *(const float4*)(rp + 4);
    xa[i][2] = *(const float4*)(rp + 32);
    xa[i][3] = *(const float4*)(rp + 36);
  }

  // ---- B fragments: Pfrag, coalesced, L2-hot.
  bf16x8 Bf[2][4];
  #pragma unroll
  for (int s = 0; s < 2; ++s)
    #pragma unroll
    for (int t = 0; t < 4; ++t)
      Bf[s][t] = *(const bf16x8*)(Pfrag + (((s*4 + t) * 64 + l) << 3));

  bf16x8 Af[4][2];
  #pragma unroll
  for (int i = 0; i < 4; ++i) {
    Af[i][0] = pack8(xa[i][0], xa[i][1]);
    Af[i][1] = pack8(xa[i][2], xa[i][3]);
  }

  float r = 0.f;
  const float* Lrow = &Lv[tid * 36];

  // ---- half 0: leaves 0..31, steps 1..31
  do_gemm<0>(Bf, Af, Lv, w, q, c);
  #pragma unroll 1
  for (int cch = 0; cch < 4; ++cch)
    do_chunk(cch * 8, Lrow, Lp4, r);

  // ---- half 1: leaves 32..63, steps 32..63 (wave-local DS ordering makes
  // the overwrite of Lv safe: all half-0 reads precede these writes in
  // program order within the owning wave).
  do_gemm<1>(Bf, Af, Lv, w, q, c);
  #pragma unroll 1
  for (int cch = 0; cch < 4; ++cch)
    do_chunk(32 + cch * 8, Lrow, Lp4, r);

  // ---- final unreflect of the last layer.
  const float sgnL = layers[62 * 8];
  out[rowbase + tid] = fmaf(sgnL, r, fmaf(-0.5f, sgnL, 0.5f));
}

// ---------------------------------------------------------------------------
extern "C" void kernel_launch(void* const* d_in, const int* in_sizes, int n_in,
                              void* d_out, int out_size, void* d_ws, size_t ws_size,
                              hipStream_t stream) {
  const float* x       = (const float*)d_in[0];
  const float* logits  = (const float*)d_in[1];
  const float* weights = (const float*)d_in[2];
  const float* biases  = (const float*)d_in[3];
  float* out = (float*)d_out;

  unsigned short* Pfrag = (unsigned short*)d_ws;              // 8 KB
  float* layers = (float*)((char*)d_ws + 8 * 64 * 8 * sizeof(unsigned short));

  const int batch = out_size;  // 262144

  hipLaunchKernelGGL(sinkhorn_kernel, dim3(1), dim3(64), 0, stream,
                     logits, weights, biases, Pfrag, layers);
  hipLaunchKernelGGL(scan_kernel, dim3(batch / 256), dim3(256), 0, stream,
                     x, Pfrag, layers, out);
}